// Round 1
// baseline (184.455 us; speedup 1.0000x reference)
//
#include <hip/hip_runtime.h>

// Per-batch segment_sum with SORTED segment ids.
//   embeddings: (B=64, S=512, D=768) fp32; segment_ids: (B,S) int32 sorted.
//   out = concat(agg[:,0] (B,D), agg[:,1:] (B,S-1,D)) — flat B*S*D floats.
//
// R3 post-mortem: one-wave-per-output left each wave with ~1 input row of
// payload behind a serialized id-load -> ballot -> emb-load chain; 61.6 us at
// 2.46 TB/s (39% of achievable) with VALUBusy 4.8% => latency/MLP-starved,
// not BW-bound. Also 64 MB of redundant id reads (each 2 KB row x 512 waves).
//
// R4: G=4 OUTPUT ROWS PER WAVE. One id-row load + 40 ballot/popcounts gives
// the 5 prefix counts pref[j] = #(seg < g0+j); the wave then streams a
// contiguous ~G-row slab (avg 4 rows = 12 KB) with all addresses known up
// front (uniform nested loop bounds -> deep load pipelining), and writes 4
// output rows. 4x fewer waves (8192 = 32/CU, full occupancy in one residency
// round), 4x the per-wave in-flight payload, 4x less id traffic. Reads and
// writes remain exactly-once and 1 KB-coalesced; no atomics.

constexpr int B  = 64;
constexpr int S  = 512;
constexpr int D  = 768;
constexpr int D4 = D / 4;          // 192 float4 per row = 64 lanes x 3
constexpr int G  = 4;              // output segments per wave
constexpr int WPB = S / G;         // 128 waves per batch
constexpr int BLOCK = 256;         // 4 waves per block

__global__ __launch_bounds__(BLOCK) void segsum_g4_kernel(
    const float4* __restrict__ emb,   // (B*S*D4)
    const int*    __restrict__ seg,   // (B*S)
    float4*       __restrict__ out) { // report (B*D4) then word (B*(S-1)*D4)
  const int wave = (blockIdx.x * BLOCK + threadIdx.x) >> 6;  // [0, B*S/G)
  const int lane = threadIdx.x & 63;
  const int b    = wave >> 7;            // wave / WPB
  const int g0   = (wave & (WPB - 1)) * G;

  // Whole id row in 2 coalesced int4 loads (L2-hot: 128 waves/b reuse it).
  const int4* row = (const int4*)(seg + b * S);  // 128 int4
  const int4 a0 = row[lane];
  const int4 a1 = row[lane + 64];

  // pref[j] = #(seg[b] < g0+j) for j=0..G — run boundaries for all G outputs.
  // 40 independent cmp+ballot+popcount; no dependent search chain.
  int pref[G + 1];
#pragma unroll
  for (int j = 0; j <= G; ++j) {
    const int t = g0 + j;
    int c = 0;
    c += __popcll(__ballot(a0.x < t));
    c += __popcll(__ballot(a0.y < t));
    c += __popcll(__ballot(a0.z < t));
    c += __popcll(__ballot(a0.w < t));
    c += __popcll(__ballot(a1.x < t));
    c += __popcll(__ballot(a1.y < t));
    c += __popcll(__ballot(a1.z < t));
    c += __popcll(__ballot(a1.w < t));
    pref[j] = c;
  }

  // Stream the contiguous slab [pref[0], pref[G]) once; runs are adjacent,
  // so p simply advances across the j-loop. Lane i owns float4 columns
  // {i, i+64, i+128}.
  const float4* p = emb + ((size_t)b * S + pref[0]) * D4 + lane;
#pragma unroll
  for (int j = 0; j < G; ++j) {
    float4 acc0 = make_float4(0.f, 0.f, 0.f, 0.f);
    float4 acc1 = acc0, acc2 = acc0;
    for (int k = pref[j]; k < pref[j + 1]; ++k) {  // wave-uniform trip count
      float4 e0 = p[0], e1 = p[64], e2 = p[128];
      acc0.x += e0.x; acc0.y += e0.y; acc0.z += e0.z; acc0.w += e0.w;
      acc1.x += e1.x; acc1.y += e1.y; acc1.z += e1.z; acc1.w += e1.w;
      acc2.x += e2.x; acc2.y += e2.y; acc2.z += e2.z; acc2.w += e2.w;
      p += D4;
    }
    const int g = g0 + j;
    float4* dst = (g == 0)
        ? out + (size_t)b * D4                                         // report_feat
        : out + (size_t)B * D4 + ((size_t)b * (S - 1) + (g - 1)) * D4; // word_feat
    dst[lane]       = acc0;
    dst[lane + 64]  = acc1;
    dst[lane + 128] = acc2;
  }
}

extern "C" void kernel_launch(void* const* d_in, const int* in_sizes, int n_in,
                              void* d_out, int out_size, void* d_ws, size_t ws_size,
                              hipStream_t stream) {
  const float4* emb = (const float4*)d_in[0];
  const int*    seg = (const int*)d_in[1];
  float4*       out = (float4*)d_out;

  const int waves  = B * S / G;                // 8192 waves, 4 outputs each
  const int blocks = waves / (BLOCK / 64);     // 2048 blocks = 8/CU resident
  segsum_g4_kernel<<<blocks, BLOCK, 0, stream>>>(emb, seg, out);
}

// Round 2
// 183.696 us; speedup vs baseline: 1.0041x; 1.0041x over previous
//
#include <hip/hip_runtime.h>

// Per-batch segment_sum with SORTED segment ids.
//   embeddings: (B=64, S=512, D=768) fp32; segment_ids: (B,S) int32 sorted.
//   out = concat(agg[:,0] (B,D), agg[:,1:] (B,S-1,D)) — flat B*S*D floats.
//
// R4 post-mortem: G=4-per-wave coarsening traded TLP for no MLP gain — the
// runtime-trip-count inner loops kept loads serialized behind the accumulate
// chain (66.6 us, BW down). Latency*residency math says either structure
// should run in a few us; the >10x gap means wave lifetime is dominated by
// phases with ZERO reads in flight.
//
// R5: VALUE-CHUNK BLOCK SCAN. One block (192 threads = 3 waves, one float4
// column per thread) owns 16 consecutive segment VALUES:
//   1. 3 waves split the 17 ballot prefix-counts (#(seg < v0+j)) over the
//      2 KB id row -> s_pref[] in LDS. All run boundaries known up front.
//   2. Stream the contiguous row slab [pref[0], pref[16]) (avg 16 rows,
//      48 KB) in fully-unrolled batches of 8 rows: 8 back-to-back
//      global_load_dwordx4 per thread, addresses independent of loaded data
//      -> deep MLP, memcpy-like issue pattern.
//   3. Flush logic is block-uniform scalar compares against precomputed
//      pref[] — no data-dependent branch ever gates a load. Empty segments
//      emit zero rows naturally; ascending row order => bitwise == reference.
// Grid = 2048 blocks = 8/CU: whole grid resident in ONE round, no churn.
// Id traffic drops 64 MB -> 4 MB.

constexpr int B  = 64;
constexpr int S  = 512;
constexpr int D  = 768;
constexpr int D4 = D / 4;            // 192 float4 per row
constexpr int VALS    = 16;          // segment values per block
constexpr int THREADS = 192;         // 3 waves; thread t owns float4 column t
constexpr int WPB     = S / VALS;    // 32 value-windows per batch
constexpr int NBLK    = B * WPB;     // 2048 blocks

__device__ __forceinline__ void facc(float4& a, const float4& e) {
  a.x += e.x; a.y += e.y; a.z += e.z; a.w += e.w;
}

__device__ __forceinline__ float4* out_row(float4* out, int b, int g) {
  return (g == 0) ? out + (size_t)b * D4
                  : out + (size_t)B * D4 + ((size_t)b * (S - 1) + (g - 1)) * D4;
}

__global__ __launch_bounds__(THREADS, 6) void segsum_scan_kernel(
    const float4* __restrict__ emb,   // (B*S*D4)
    const int*    __restrict__ seg,   // (B*S)
    float4*       __restrict__ out) { // report (B*D4) then word (B*(S-1)*D4)
  const int b    = blockIdx.x >> 5;             // blockIdx / WPB
  const int v0   = (blockIdx.x & (WPB - 1)) * VALS;
  const int tid  = threadIdx.x;
  const int lane = tid & 63;
  const int wav  = tid >> 6;                    // 0..2

  __shared__ int s_pref[VALS + 1];

  // Each wave holds the full 2 KB id row (L1-hot; 2 coalesced int4 loads) and
  // computes ~6 of the 17 prefix counts via independent ballot/popcount.
  const int4* row = (const int4*)(seg + b * S); // 128 int4
  const int4 a0 = row[lane];
  const int4 a1 = row[lane + 64];
  for (int j = wav; j <= VALS; j += 3) {
    const int t = v0 + j;
    int c = 0;
    c += __popcll(__ballot(a0.x < t));
    c += __popcll(__ballot(a0.y < t));
    c += __popcll(__ballot(a0.z < t));
    c += __popcll(__ballot(a0.w < t));
    c += __popcll(__ballot(a1.x < t));
    c += __popcll(__ballot(a1.y < t));
    c += __popcll(__ballot(a1.z < t));
    c += __popcll(__ballot(a1.w < t));
    if (lane == 0) s_pref[j] = c;
  }
  __syncthreads();

  const int rbeg = s_pref[0];
  const int rend = s_pref[VALS];

  const float4* base = emb + (size_t)b * S * D4 + tid;
  float4 acc = make_float4(0.f, 0.f, 0.f, 0.f);
  int v   = 0;
  int nxt = s_pref[1];                          // end row of value v's run

  for (int r = rbeg; r < rend; r += 8) {
    // Batch of 8 rows: all addresses known now -> 8 loads issued back-to-back.
    float4 e[8];
#pragma unroll
    for (int u = 0; u < 8; ++u) {
      int rr = r + u;
      rr = rr < rend ? rr : rend - 1;           // clamp: L1-hot re-read, skipped below
      e[u] = base[(size_t)rr * D4];
    }
#pragma unroll
    for (int u = 0; u < 8; ++u) {
      const int rr = r + u;
      if (rr >= rend) break;                    // block-uniform
      while (rr == nxt) {                       // value v's run ended: flush
        out_row(out, b, v0 + v)[tid] = acc;     // zero row if run was empty
        acc = make_float4(0.f, 0.f, 0.f, 0.f);
        ++v;                                    // v <= 15 while rr < rend
        nxt = s_pref[v + 1];                    // uniform LDS broadcast
      }
      facc(acc, e[u]);
    }
  }

  // Drain: value v's run ends at rend (store acc), remaining values are empty.
  for (; v < VALS; ++v) {
    out_row(out, b, v0 + v)[tid] = acc;
    acc = make_float4(0.f, 0.f, 0.f, 0.f);
  }
}

extern "C" void kernel_launch(void* const* d_in, const int* in_sizes, int n_in,
                              void* d_out, int out_size, void* d_ws, size_t ws_size,
                              hipStream_t stream) {
  const float4* emb = (const float4*)d_in[0];
  const int*    seg = (const int*)d_in[1];
  float4*       out = (float4*)d_out;
  segsum_scan_kernel<<<NBLK, THREADS, 0, stream>>>(emb, seg, out);
}

// Round 4
// 178.406 us; speedup vs baseline: 1.0339x; 1.0296x over previous
//
#include <hip/hip_runtime.h>

// Per-batch segment_sum with SORTED segment ids.
//   embeddings: (B=64, S=512, D=768) fp32; segment_ids: (B,S) int32 sorted.
//   out = concat(agg[:,0] (B,D), agg[:,1:] (B,S-1,D)) — flat B*S*D floats.
//
// R4/R5 post-mortem: three structurally different kernels (1 wave/row, G=4
// coarsened, block-scan with 8-deep batched loads) all land at 62-66 us,
// ~2.4 TB/s, VALUBusy 3-5% — duration is INVARIANT to execution structure.
// The tell is FETCH_SIZE = 49.7 MB: embeddings (100.7 MB, L3-fit, re-read
// every iteration) miss L3 for HALF their bytes, because the 100.7 MB output
// write stream write-allocates in L2/L3 each dispatch and evicts them; the
// dirty writebacks then contend with demand reads on the fabric.
//
// R6 = R3 (best measured, 61.6 us) + NONTEMPORAL OUTPUT STORES (single-
// variable change). The output has zero kernel-side reuse; streaming it past
// L2/L3 allocation (gfx950 `nt`) keeps the embeddings L3-resident and removes
// writeback/read contention. Prediction: FETCH 49.7 -> <~15 MB, dur -> 45-52 us.
// (R6a: __builtin_nontemporal_store needs a clang-native vector type, not
// HIP_vector_type — cast through ext_vector_type(4). Same dwordx4 nt store.)

constexpr int B  = 64;
constexpr int S  = 512;
constexpr int D  = 768;
constexpr int D4 = D / 4;          // 192 float4 per row = 64 lanes x 3
constexpr int BLOCK = 256;         // 4 waves per block

typedef float f32x4 __attribute__((ext_vector_type(4)));

__device__ __forceinline__ void nt_store4(float4* p, const float4& v) {
  f32x4 t = {v.x, v.y, v.z, v.w};
  __builtin_nontemporal_store(t, (f32x4*)p);
}

__global__ __launch_bounds__(BLOCK) void segsum_wave_nt_kernel(
    const float4* __restrict__ emb,   // (B*S*D4)
    const int*    __restrict__ seg,   // (B*S)
    float4*       __restrict__ out) { // report (B*D4) then word (B*(S-1)*D4)
  const int wave = (blockIdx.x * BLOCK + threadIdx.x) >> 6;  // [0, B*S)
  const int lane = threadIdx.x & 63;
  const int b    = wave >> 9;        // wave / S
  const int g    = wave & (S - 1);   // wave % S

  // Whole id row in 2 coalesced int4 loads (L1/L2-hot: 512 waves/b reuse it).
  const int4* row = (const int4*)(seg + b * S);  // 128 int4
  const int4 a0 = row[lane];
  const int4 a1 = row[lane + 64];

  // start = #(x < g), end = #(x <= g). 16 independent cmp/ballot/popcount.
  int start = 0, end = 0;
  start += __popcll(__ballot(a0.x < g));
  start += __popcll(__ballot(a0.y < g));
  start += __popcll(__ballot(a0.z < g));
  start += __popcll(__ballot(a0.w < g));
  start += __popcll(__ballot(a1.x < g));
  start += __popcll(__ballot(a1.y < g));
  start += __popcll(__ballot(a1.z < g));
  start += __popcll(__ballot(a1.w < g));
  end   += __popcll(__ballot(a0.x <= g));
  end   += __popcll(__ballot(a0.y <= g));
  end   += __popcll(__ballot(a0.z <= g));
  end   += __popcll(__ballot(a0.w <= g));
  end   += __popcll(__ballot(a1.x <= g));
  end   += __popcll(__ballot(a1.y <= g));
  end   += __popcll(__ballot(a1.z <= g));
  end   += __popcll(__ballot(a1.w <= g));

  // Stream the run: lane i owns float4 columns {i, i+64, i+128}.
  float4 acc0 = make_float4(0.f, 0.f, 0.f, 0.f);
  float4 acc1 = acc0, acc2 = acc0;
  const float4* p = emb + (size_t)(b * S + start) * D4 + lane;
  for (int s = start; s < end; ++s) {          // wave-uniform trip count
    float4 e0 = p[0], e1 = p[64], e2 = p[128];
    acc0.x += e0.x; acc0.y += e0.y; acc0.z += e0.z; acc0.w += e0.w;
    acc1.x += e1.x; acc1.y += e1.y; acc1.z += e1.z; acc1.w += e1.w;
    acc2.x += e2.x; acc2.y += e2.y; acc2.z += e2.z; acc2.w += e2.w;
    p += D4;
  }

  // Nontemporal stores: output has zero kernel-side reuse — stream past
  // L2/L3 allocation so the embeddings stay L3-resident across iterations.
  float4* dst = (g == 0)
      ? out + (size_t)b * D4                                        // report_feat
      : out + (size_t)B * D4 + ((size_t)b * (S - 1) + (g - 1)) * D4; // word_feat
  nt_store4(dst + lane,       acc0);
  nt_store4(dst + lane + 64,  acc1);
  nt_store4(dst + lane + 128, acc2);
}

extern "C" void kernel_launch(void* const* d_in, const int* in_sizes, int n_in,
                              void* d_out, int out_size, void* d_ws, size_t ws_size,
                              hipStream_t stream) {
  const float4* emb = (const float4*)d_in[0];
  const int*    seg = (const int*)d_in[1];
  float4*       out = (float4*)d_out;

  const int waves  = B * S;                    // 32768 output rows
  const int blocks = waves / (BLOCK / 64);     // 8192 blocks
  segsum_wave_nt_kernel<<<blocks, BLOCK, 0, stream>>>(emb, seg, out);
}